// Round 11
// baseline (122.728 us; speedup 1.0000x reference)
//
#include <hip/hip_runtime.h>

typedef _Float16 half8 __attribute__((ext_vector_type(8)));
typedef _Float16 half4 __attribute__((ext_vector_type(4)));
typedef float floatx4 __attribute__((ext_vector_type(4)));

static constexpr int NB  = 32;    // batches
static constexpr int NP  = 4096;  // points per batch
static constexpr int DD  = 128;   // dim
static constexpr int KC  = 64;    // clusters
static constexpr int TN  = 64;    // points per tile
static constexpr int BPB = 24;    // blocks per batch: 16 blocks x 3 tiles + 8 x 2
                                  // -> grid = 24*32 = 768 = EXACTLY 3 blocks/CU,
                                  // one scheduling generation (R10 ran 1024
                                  // blocks = 2 unbalanced generations)
static constexpr int SLOTS = BPB; // partial slots per batch
static constexpr int STP = 72;    // sxt / sat pitch (halfwords).  NOTE: stride
                                  // 36 dwords ≡ 4 (mod 32 banks) is what makes
                                  // the XOR-swizzled b128 reads 2-way-max; do
                                  // not "optimize" to 64.

#define ALPHA_  100.0f
#define LOG2E_  1.44269504088896f

// Workgroup barrier that waits ONLY on LDS (lgkmcnt), leaving prefetched
// global loads in flight. __syncthreads() would emit s_waitcnt vmcnt(0)
// and drain the prefetch on the critical path.
#define LGKM_BARRIER() asm volatile("s_waitcnt lgkmcnt(0)\ns_barrier" ::: "memory")

// Kernel 1: distances -> softmax -> block-private vlad partial.
//
// REGISTER BUDGET (gfx950 unified VGPR/AGPR file — the R7 lesson): centroid
// frags live in LDS (schi), NOT registers. Peak live set ~120 regs < the
// 170-reg cap of __launch_bounds__(256,3); chi-in-regs (+64) spills.
// PARTIALS IN FP16 (R10): quantization ~5e-6 on output, 100x under the
// bf16-ulp compare floor.
__global__ __launch_bounds__(256, 3)
void vlad_main(const float* __restrict__ xg, const float* __restrict__ cg,
               _Float16* __restrict__ vp, float* __restrict__ cpart)
{
    __shared__ __align__(16) _Float16 sxt[DD][STP];   // x^T [d][n^swz]      18.0 KB
    __shared__ __align__(16) _Float16 sat[KC][STP];   // a^T [k][n^swz]       9.0 KB
    __shared__ __align__(16) _Float16 schi[KC][DD];   // centroid fp16 swz   16.0 KB
    __shared__ float sc2[KC];

    const int tid  = threadIdx.x;
    const int lane = tid & 63;
    const int w    = tid >> 6;
    const int l15  = lane & 15;
    const int quad = lane >> 4;
    const int cswz = l15 & 7;             // schi XOR key for this lane's rows
    const int b    = blockIdx.y;
    const int s    = blockIdx.x;          // slot within batch (0..23)
    // tile range for this slot: slots 0..15 take 3 tiles, 16..23 take 2
    const int t0   = (s < 16) ? s*3 : 48 + (s - 16)*2;
    const int ntl  = (s < 16) ? 3 : 2;
    const float* xb = xg + (size_t)b * NP * DD;

    const int nloc = w*16 + l15;
    const int scol = nloc ^ (quad << 4);
    const float* xpt = xb + (size_t)(t0*TN + nloc)*DD + quad*8;

    // ---- issue x tile-0 loads FIRST (cold HBM; hide under centroid prep).
    //      Nontemporal: every x byte is read exactly once device-wide. ----
    floatx4 fa[4], fb[4];
#pragma unroll
    for (int ks = 0; ks < 4; ++ks) {
        fa[ks] = __builtin_nontemporal_load((const floatx4*)(xpt + ks*32));
        fb[ks] = __builtin_nontemporal_load((const floatx4*)(xpt + ks*32 + 4));
    }

    // ---- centroid prep (wave 0 only): fp16 frags -> schi (swizzled),
    //      exact fp32 c2 -> sc2 ----
    if (w == 0) {
#pragma unroll
        for (int mt = 0; mt < 4; ++mt) {
            float c2p = 0.f;
#pragma unroll
            for (int ks = 0; ks < 4; ++ks) {
                const float* p = cg + (mt*16 + l15)*DD + ks*32 + quad*8;
                floatx4 a  = *(const floatx4*)p;
                floatx4 bb = *(const floatx4*)(p + 4);
                half8 h;
                h[0]=(_Float16)a[0];  h[1]=(_Float16)a[1];  h[2]=(_Float16)a[2];  h[3]=(_Float16)a[3];
                h[4]=(_Float16)bb[0]; h[5]=(_Float16)bb[1]; h[6]=(_Float16)bb[2]; h[7]=(_Float16)bb[3];
                *(half8*)&schi[mt*16 + l15][((ks*4 + quad) ^ cswz) * 8] = h;
                c2p += a[0]*a[0] + a[1]*a[1] + a[2]*a[2] + a[3]*a[3]
                     + bb[0]*bb[0] + bb[1]*bb[1] + bb[2]*bb[2] + bb[3]*bb[3];
            }
            c2p += __shfl_xor(c2p, 16);
            c2p += __shfl_xor(c2p, 32);
            if (quad == 0) sc2[mt*16 + l15] = c2p;
        }
    }
    LGKM_BARRIER();   // schi / sc2 ready (x tile-0 loads stay in flight)

    floatx4 acc2[8];   // vlad partial: row k = w*16+quad*4+r, col d = nt*16+l15
#pragma unroll
    for (int i = 0; i < 8; ++i) acc2[i] = (floatx4){0.f, 0.f, 0.f, 0.f};
    floatx4 accs = (floatx4){0.f, 0.f, 0.f, 0.f};  // colsum via ones-column MFMA

    half8 onesf;       // B[point][col] = (col==0)
#pragma unroll
    for (int j = 0; j < 8; ++j) onesf[j] = (_Float16)((l15 == 0) ? 1.0f : 0.0f);

    for (int tt = 0; tt < ntl; ++tt) {
        // ---- convert staged fp32 -> fp16 frags; per-lane ssq ----
        half8 xf[4];
        float ssq = 0.f;
#pragma unroll
        for (int ks = 0; ks < 4; ++ks) {
            half8 h;
            h[0]=(_Float16)fa[ks][0]; h[1]=(_Float16)fa[ks][1];
            h[2]=(_Float16)fa[ks][2]; h[3]=(_Float16)fa[ks][3];
            h[4]=(_Float16)fb[ks][0]; h[5]=(_Float16)fb[ks][1];
            h[6]=(_Float16)fb[ks][2]; h[7]=(_Float16)fb[ks][3];
            xf[ks] = h;
            ssq += fa[ks][0]*fa[ks][0] + fa[ks][1]*fa[ks][1] + fa[ks][2]*fa[ks][2] + fa[ks][3]*fa[ks][3]
                 + fb[ks][0]*fb[ks][0] + fb[ks][1]*fb[ks][1] + fb[ks][2]*fb[ks][2] + fb[ks][3]*fb[ks][3];
        }

        // ---- prefetch next tile; stays in flight across BOTH lgkm barriers ----
        if (tt + 1 < ntl) {
            const float* xr = xpt + (size_t)(tt + 1) * TN * DD;
#pragma unroll
            for (int ks = 0; ks < 4; ++ks) {
                fa[ks] = __builtin_nontemporal_load((const floatx4*)(xr + ks*32));
                fb[ks] = __builtin_nontemporal_load((const floatx4*)(xr + ks*32 + 4));
            }
        }

        // ---- barrier A: all waves done reading LDS of previous tile ----
        if (tt) LGKM_BARRIER();

        // ---- write x^T (swizzled; 2-way max = free) ----
#pragma unroll
        for (int ks = 0; ks < 4; ++ks)
#pragma unroll
            for (int j = 0; j < 8; ++j)
                sxt[ks*32 + quad*8 + j][scol] = xf[ks][j];

        // ---- GEMM1: S^T[cluster][point]; centroid A-frags streamed from LDS ----
        floatx4 acc1[4];
#pragma unroll
        for (int mt = 0; mt < 4; ++mt) acc1[mt] = (floatx4){0.f, 0.f, 0.f, 0.f};
#pragma unroll
        for (int ks = 0; ks < 4; ++ks)
#pragma unroll
            for (int mt = 0; mt < 4; ++mt) {
                half8 cf = *(const half8*)&schi[mt*16 + l15][((ks*4 + quad) ^ cswz) * 8];
                acc1[mt] = __builtin_amdgcn_mfma_f32_16x16x32_f16(cf, xf[ks], acc1[mt], 0, 0, 0);
            }
        ssq += __shfl_xor(ssq, 16);
        ssq += __shfl_xor(ssq, 32);

        // ---- softmax over 64 clusters for this lane's point ----
        float dist[4][4];
#pragma unroll
        for (int mt = 0; mt < 4; ++mt) {
            floatx4 c2v = *(const floatx4*)&sc2[mt*16 + quad*4];
#pragma unroll
            for (int r = 0; r < 4; ++r) {
                float d2 = ssq + c2v[r] - 2.f*acc1[mt][r];
                dist[mt][r] = sqrtf(fmaxf(d2, 0.f));
            }
        }
        float dmin = dist[0][0];
#pragma unroll
        for (int mt = 0; mt < 4; ++mt)
#pragma unroll
            for (int r = 0; r < 4; ++r) dmin = fminf(dmin, dist[mt][r]);
        dmin = fminf(dmin, __shfl_xor(dmin, 16));
        dmin = fminf(dmin, __shfl_xor(dmin, 32));
        float pv[4][4];
        float psum = 0.f;
#pragma unroll
        for (int mt = 0; mt < 4; ++mt)
#pragma unroll
            for (int r = 0; r < 4; ++r) {
                float e = exp2f((dmin - dist[mt][r]) * (ALPHA_ * LOG2E_));
                pv[mt][r] = e; psum += e;
            }
        psum += __shfl_xor(psum, 16);
        psum += __shfl_xor(psum, 32);
        float invs = 1.0f / psum;
#pragma unroll
        for (int mt = 0; mt < 4; ++mt)
#pragma unroll
            for (int r = 0; r < 4; ++r)
                sat[mt*16 + quad*4 + r][scol] = (_Float16)(pv[mt][r] * invs);

        LGKM_BARRIER();   // barrier B: sxt/sat visible; prefetch NOT drained

        // ---- GEMM2: vlad[k][d] += a^T · x ; colsum via ones column ----
#pragma unroll
        for (int ks2 = 0; ks2 < 2; ++ks2) {
            const int nbase = ks2*32 + quad*8;
            half8 af = *(const half8*)&sat[w*16 + l15][nbase ^ ((l15 >> 2) << 4)];
            accs = __builtin_amdgcn_mfma_f32_16x16x32_f16(af, onesf, accs, 0, 0, 0);
#pragma unroll
            for (int nt = 0; nt < 8; ++nt) {
                const int d = nt*16 + l15;
                half8 bf = *(const half8*)&sxt[d][nbase ^ (((d >> 3) & 3) << 4)];
                acc2[nt] = __builtin_amdgcn_mfma_f32_16x16x32_f16(af, bf, acc2[nt], 0, 0, 0);
            }
        }
    }

    // ---- epilogue: fp16 nontemporal stores into this block's slot ----
    _Float16* slot = vp + ((size_t)b*SLOTS + s) * (KC*DD);
#pragma unroll
    for (int nt = 0; nt < 8; ++nt)
#pragma unroll
        for (int r = 0; r < 4; ++r) {
            int k = w*16 + quad*4 + r;
            int d = nt*16 + l15;
            __builtin_nontemporal_store((_Float16)acc2[nt][r], &slot[k*DD + d]);
        }
    if (l15 == 0) {
#pragma unroll
        for (int r = 0; r < 4; ++r)
            __builtin_nontemporal_store(accs[r],
                &cpart[((size_t)b*SLOTS + s)*KC + w*16 + quad*4 + r]);
    }
}

// Kernel 2: reduce fp16 partials (8 blocks/batch), subtract colsum*c, write
// reduced fp32 vlad + per-chunk sum-of-squares.
__global__ __launch_bounds__(256)
void vlad_reduce(const _Float16* __restrict__ vp, const float* __restrict__ cpart,
                 const float* __restrict__ cg, float* __restrict__ vfull,
                 float* __restrict__ ssp)
{
    __shared__ float scs[KC];
    __shared__ float red[4];
    const int b   = blockIdx.x >> 3;
    const int q   = blockIdx.x & 7;       // 1024-element chunk
    const int tid = threadIdx.x;

    if (tid < KC) {
        float cs = 0.f;
#pragma unroll
        for (int si = 0; si < SLOTS; ++si)
            cs += cpart[((size_t)b*SLOTS + si)*KC + tid];
        scs[tid] = cs;
    }
    __syncthreads();

    const int idx = q*1024 + tid*4;       // 4 consecutive elements per thread
    const _Float16* vpb = vp + (size_t)b*SLOTS*(KC*DD) + idx;
    floatx4 a = (floatx4){0.f, 0.f, 0.f, 0.f};
#pragma unroll
    for (int si = 0; si < SLOTS; ++si) {
        half4 t = __builtin_nontemporal_load((const half4*)(vpb + (size_t)si*(KC*DD)));
        a += __builtin_convertvector(t, floatx4);
    }
    float cs = scs[idx >> 7];             // same cluster for all 4 (128 | idx)
    floatx4 cv = *(const floatx4*)(cg + idx);
    a -= cs * cv;
    *(floatx4*)(vfull + (size_t)b*(KC*DD) + idx) = a;
    float ss = a[0]*a[0] + a[1]*a[1] + a[2]*a[2] + a[3]*a[3];
#pragma unroll
    for (int m = 1; m < 64; m <<= 1) ss += __shfl_xor(ss, m);
    if ((tid & 63) == 0) red[tid >> 6] = ss;
    __syncthreads();
    if (tid == 0) ssp[b*8 + q] = red[0] + red[1] + red[2] + red[3];
}

// Kernel 3: L2-normalize per batch (widened to 256 blocks)
__global__ __launch_bounds__(256)
void vlad_norm(const float* __restrict__ vfull, const float* __restrict__ ssp,
               float* __restrict__ out)
{
    const int b   = blockIdx.x >> 3;
    const int q   = blockIdx.x & 7;
    const int tid = threadIdx.x;
    float tot = 0.f;
#pragma unroll
    for (int k = 0; k < 8; ++k) tot += ssp[b*8 + k];
    float scale = 1.0f / fmaxf(sqrtf(tot), 1e-12f);
    const int idx = q*1024 + tid*4;
    floatx4 v = *(const floatx4*)(vfull + (size_t)b*(KC*DD) + idx);
    v *= scale;
    *(floatx4*)(out + (size_t)b*(KC*DD) + idx) = v;
}

extern "C" void kernel_launch(void* const* d_in, const int* in_sizes, int n_in,
                              void* d_out, int out_size, void* d_ws, size_t ws_size,
                              hipStream_t stream)
{
    (void)in_sizes; (void)n_in; (void)out_size; (void)ws_size;
    const float* x = (const float*)d_in[0];
    const float* c = (const float*)d_in[1];
    float* out      = (float*)d_out;
    _Float16* vp    = (_Float16*)d_ws;                       // [32][24][64][128] fp16 = 12.6 MB
    float* cpart    = (float*)(vp + (size_t)NB*SLOTS*KC*DD); // [32][24][64]
    float* vfull    = cpart + (size_t)NB*SLOTS*KC;           // [32][8192]
    float* ssp      = vfull + (size_t)NB*KC*DD;              // [32][8]

    vlad_main<<<dim3(BPB, NB), 256, 0, stream>>>(x, c, vp, cpart);
    vlad_reduce<<<NB*8, 256, 0, stream>>>(vp, cpart, c, vfull, ssp);
    vlad_norm<<<NB*8, 256, 0, stream>>>(vfull, ssp, out);
}